// Round 4
// baseline (509.180 us; speedup 1.0000x reference)
//
#include <hip/hip_runtime.h>
#include <math.h>

#define ALPHA 0.2f
#define S_DIM 64
#define D_DIM 128
#define GPB 4   // groups processed per block (persistent-ish, software-pipelined)

// 256 threads = 8 row-groups (g) x 32 float4-chunks (c). Each block handles
// GPB consecutive groups; group i+1's global loads are issued immediately
// after group i's cv registers are consumed, so group i's serial tail
// (reduce/softmax/phase-2/store) overlaps group i+1's 2 MB stream.
__global__ __launch_bounds__(256) void gat_fused_kernel(
    const float* __restrict__ center,
    const float* __restrict__ nbr,
    const float* __restrict__ a,
    float* __restrict__ out,
    int n_total)
{
    const int t = threadIdx.x;       // 0..255
    const int c = t & 31;            // float4-chunk within a row (0..31)
    const int g = t >> 5;            // 0..7
    const int d0 = c * 4;            // starting feature index of my chunk
    const int n0 = blockIdx.x * GPB;

    __shared__ float e_lds[S_DIM];
    __shared__ float att_lds[S_DIM];
    __shared__ float out_lds[8 * D_DIM];   // per-g partial outputs

    // a slices for my d-chunk (constant across k since (t+256k)%32 == t%32)
    const float4 a0 = *(const float4*)(a + d0);
    const float4 a1 = *(const float4*)(a + D_DIM + d0);

    float4 cv[8];          // center chunks (single-buffered: consumed early)
    float4 nv[8], nv2[8];  // nbr chunks (double-buffered: needed in phase 2)

    // ---- prologue: load first group's data ----
    {
        const float4* c4p = (const float4*)(center + (size_t)n0 * (S_DIM * D_DIM));
        const float4* n4p = (const float4*)(nbr    + (size_t)n0 * (S_DIM * D_DIM));
#pragma unroll
        for (int k = 0; k < 8; ++k) {
            const int f = t + 256 * k;   // coalesced flat float4 index
            cv[k] = c4p[f];
            nv[k] = n4p[f];
        }
    }

#pragma unroll 1
    for (int i = 0; i < GPB; ++i) {
        const int n = n0 + i;
        if (n >= n_total) break;

        // ---- consume cv+nv into partials (frees cv registers) ----
        float partial[8];
#pragma unroll
        for (int k = 0; k < 8; ++k) {
            partial[k] = cv[k].x * a0.x + cv[k].y * a0.y + cv[k].z * a0.z + cv[k].w * a0.w
                       + nv[k].x * a1.x + nv[k].y * a1.y + nv[k].z * a1.z + nv[k].w * a1.w;
        }

        // ---- prefetch next group (overlaps everything below) ----
        if (i + 1 < GPB && n + 1 < n_total) {
            const float4* c4p = (const float4*)(center + (size_t)(n + 1) * (S_DIM * D_DIM));
            const float4* n4p = (const float4*)(nbr    + (size_t)(n + 1) * (S_DIM * D_DIM));
#pragma unroll
            for (int k = 0; k < 8; ++k) {
                const int f = t + 256 * k;
                cv[k]  = c4p[f];    // WAR on cv: issues after FMAs read it
                nv2[k] = n4p[f];
            }
        }

        // ---- reduce each partial across its 32-lane group -> e[s], s = g+8k ----
#pragma unroll
        for (int k = 0; k < 8; ++k) {
            float v = partial[k];
            v += __shfl_xor(v, 16);
            v += __shfl_xor(v, 8);
            v += __shfl_xor(v, 4);
            v += __shfl_xor(v, 2);
            v += __shfl_xor(v, 1);
            if (c == 0) e_lds[g + 8 * k] = v;
        }
        __syncthreads();

        // ---- softmax over S=64 by wave 0 ----
        if (t < 64) {
            float v = e_lds[t];
            v = (v > 0.0f) ? v : ALPHA * v;         // leaky_relu
            float m = v;
            m = fmaxf(m, __shfl_xor(m, 32));
            m = fmaxf(m, __shfl_xor(m, 16));
            m = fmaxf(m, __shfl_xor(m, 8));
            m = fmaxf(m, __shfl_xor(m, 4));
            m = fmaxf(m, __shfl_xor(m, 2));
            m = fmaxf(m, __shfl_xor(m, 1));
            const float ex = expf(v - m);
            float sum = ex;
            sum += __shfl_xor(sum, 32);
            sum += __shfl_xor(sum, 16);
            sum += __shfl_xor(sum, 8);
            sum += __shfl_xor(sum, 4);
            sum += __shfl_xor(sum, 2);
            sum += __shfl_xor(sum, 1);
            att_lds[t] = ex / sum;
        }
        __syncthreads();

        // ---- phase 2: weighted sum of register-resident nbr chunks ----
        float4 o = make_float4(0.f, 0.f, 0.f, 0.f);
#pragma unroll
        for (int k = 0; k < 8; ++k) {
            const float w = att_lds[g + 8 * k];     // broadcast within 32-lane group
            o.x += w * nv[k].x;
            o.y += w * nv[k].y;
            o.z += w * nv[k].z;
            o.w += w * nv[k].w;
        }
        *(float4*)(out_lds + g * D_DIM + d0) = o;   // unique (g,c) slot
        __syncthreads();

        // ---- final cross-g reduction + coalesced store ----
        if (t < 32) {
            float4 s = make_float4(0.f, 0.f, 0.f, 0.f);
#pragma unroll
            for (int gg = 0; gg < 8; ++gg) {
                const float4 v = *(const float4*)(out_lds + gg * D_DIM + t * 4);
                s.x += v.x; s.y += v.y; s.z += v.z; s.w += v.w;
            }
            *(float4*)(out + (size_t)n * D_DIM + t * 4) = s;
        }
        // No trailing barrier needed: next iteration's first LDS write (e_lds)
        // doesn't alias out_lds, and its own barrier joins the t<32 threads
        // before out_lds is overwritten (two barriers later).

        // ---- rotate nbr buffer ----
        if (i + 1 < GPB) {
#pragma unroll
            for (int k = 0; k < 8; ++k) nv[k] = nv2[k];
        }
    }
}

extern "C" void kernel_launch(void* const* d_in, const int* in_sizes, int n_in,
                              void* d_out, int out_size, void* d_ws, size_t ws_size,
                              hipStream_t stream) {
    const float* center = (const float*)d_in[0];
    const float* nbr    = (const float*)d_in[1];
    const float* a      = (const float*)d_in[2];
    float* out = (float*)d_out;

    // Unit-independent N (verified round 3: same dur as legacy formula, N=8192):
    // in_sizes[0]/in_sizes[2] = (N*S*D)/(2*D) = N*32 in elements or bytes alike.
    int N;
    if (n_in >= 3 && in_sizes[2] > 0) {
        N = (in_sizes[0] / in_sizes[2]) / 32;
    } else {
        N = in_sizes[0] / (S_DIM * D_DIM);
    }
    if (N < 1) N = 1;

    const int grid = (N + GPB - 1) / GPB;   // 2048 for N=8192
    gat_fused_kernel<<<grid, 256, 0, stream>>>(center, nbr, a, out, N);
}